// Round 4
// baseline (529.592 us; speedup 1.0000x reference)
//
#include <hip/hip_runtime.h>

#define NB     50000
#define NB4    12500
#define BATCH  256
#define NCYC   20000
#define QSCALE  (127.0f / 3.14159265358979f)
#define DQSCALE (3.14159265358979f / 127.0f)

// ---- fused: transpose + atan2 + int8 quantize -> th[NB][BATCH] ------------
// atan2(g*s, c) = g * atan2(s, c) for g=+-1, so one atan2 per (b, branch).
// Tile: 64 b x 64 nb. Block 256. Also zeroes the arrival counter for main.
__global__ __launch_bounds__(256) void theta_k(
        const float4* __restrict__ c4, const float4* __restrict__ s4,
        signed char* __restrict__ th, int* __restrict__ counter) {
    if (blockIdx.x == 0 && blockIdx.y == 0 && threadIdx.x == 0) *counter = 0;
    __shared__ signed char t[64][68];       // [b_local][nb_local], 68 = 4*17 (aligned, odd word stride)
    const int u    = threadIdx.x;
    const int col4 = u & 15;                // nb4 within tile
    const int brow = u >> 4;                // 0..15
    const int x4   = blockIdx.x * 16 + col4;
    const int bb   = blockIdx.y * 64;

    if (x4 < NB4) {
        #pragma unroll
        for (int j = 0; j < 4; ++j) {
            const int bl = brow + 16 * j;   // b_local 0..63
            const float4 vc = c4[(size_t)(bb + bl) * NB4 + x4];
            const float4 vs = s4[(size_t)(bb + bl) * NB4 + x4];
            char4 q;
            q.x = (signed char)__float2int_rn(atan2f(vs.x, vc.x) * QSCALE);
            q.y = (signed char)__float2int_rn(atan2f(vs.y, vc.y) * QSCALE);
            q.z = (signed char)__float2int_rn(atan2f(vs.z, vc.z) * QSCALE);
            q.w = (signed char)__float2int_rn(atan2f(vs.w, vc.w) * QSCALE);
            *reinterpret_cast<char4*>(&t[bl][4 * col4]) = q;
        }
    }
    __syncthreads();
    // store phase: 16 lanes cover 64 consecutive b (64B) per nb
    const int g   = u & 15;                 // char4 group along b
    const int nb0 = u >> 4;                 // 0..15
    #pragma unroll
    for (int j = 0; j < 4; ++j) {
        const int nbl = nb0 + 16 * j;       // 0..63
        const int nb  = blockIdx.x * 64 + nbl;
        if (nb < NB) {
            char4 v;
            v.x = t[4 * g + 0][nbl];
            v.y = t[4 * g + 1][nbl];
            v.z = t[4 * g + 2][nbl];
            v.w = t[4 * g + 3][nbl];
            *reinterpret_cast<char4*>(&th[(size_t)nb * BATCH + bb + 4 * g]) = v;
        }
    }
}

// ---- main: wave per row (4/block), self-computed bounds, fused final ------
__global__ __launch_bounds__(256) void kvl_main_k(
        const signed char* __restrict__ th,
        const float* __restrict__ signs, const int* __restrict__ inds,
        const int* __restrict__ rows, int E,
        float* __restrict__ partials, int* __restrict__ counter,
        float* __restrict__ out) {
    __shared__ int bnd[5];
    const int tid = threadIdx.x;
    const int r0  = blockIdx.x * 4;
    if (tid < 5) {
        const int target = r0 + tid;
        int lo = 0, hi = E;
        while (lo < hi) { const int m = (lo + hi) >> 1; if (rows[m] < target) lo = m + 1; else hi = m; }
        bnd[tid] = lo;
    }
    __syncthreads();
    const int wave  = tid >> 6;
    const int lane  = tid & 63;
    const int start = bnd[wave];
    const int end   = bnd[wave + 1];

    float a0 = 0.f, a1 = 0.f, a2 = 0.f, a3 = 0.f;
    int e = start;
    for (; e + 2 <= end; e += 2) {
        const int   i0 = inds[e],  i1 = inds[e + 1];
        const float g0 = signs[e] * DQSCALE, g1 = signs[e + 1] * DQSCALE;
        const unsigned int u0 = *reinterpret_cast<const unsigned int*>(&th[(size_t)i0 * BATCH + lane * 4]);
        const unsigned int u1 = *reinterpret_cast<const unsigned int*>(&th[(size_t)i1 * BATCH + lane * 4]);
        a0 += g0 * (float)(signed char)(u0      ) + g1 * (float)(signed char)(u1      );
        a1 += g0 * (float)(signed char)(u0 >>  8) + g1 * (float)(signed char)(u1 >>  8);
        a2 += g0 * (float)(signed char)(u0 >> 16) + g1 * (float)(signed char)(u1 >> 16);
        a3 += g0 * (float)(signed char)(u0 >> 24) + g1 * (float)(signed char)(u1 >> 24);
    }
    if (e < end) {
        const float g0 = signs[e] * DQSCALE;
        const unsigned int u0 = *reinterpret_cast<const unsigned int*>(&th[(size_t)inds[e] * BATCH + lane * 4]);
        a0 += g0 * (float)(signed char)(u0      );
        a1 += g0 * (float)(signed char)(u0 >>  8);
        a2 += g0 * (float)(signed char)(u0 >> 16);
        a3 += g0 * (float)(signed char)(u0 >> 24);
    }
    float v = fabsf(a0) + fabsf(a1) + fabsf(a2) + fabsf(a3);
    #pragma unroll
    for (int off = 32; off > 0; off >>= 1)
        v += __shfl_down(v, off, 64);
    if (lane == 0) partials[r0 + wave] = v;

    // ---- last-block-done final reduction (device-scope fences, G16) ----
    __threadfence();                 // each thread: order its partial store device-wide
    __syncthreads();
    __shared__ int lastFlag;
    if (tid == 0) lastFlag = (atomicAdd(counter, 1) == (int)gridDim.x - 1);
    __syncthreads();
    if (lastFlag) {
        __threadfence();
        const volatile float* vp = partials;
        float v2 = 0.f;
        for (int i = tid; i < NCYC; i += 256) v2 += vp[i];
        #pragma unroll
        for (int off = 32; off > 0; off >>= 1)
            v2 += __shfl_down(v2, off, 64);
        __shared__ float ws2[4];
        if ((tid & 63) == 0) ws2[tid >> 6] = v2;
        __syncthreads();
        if (tid == 0)
            out[0] = (ws2[0] + ws2[1] + ws2[2] + ws2[3]) *
                     (1.0f / ((float)NCYC * (float)BATCH));
    }
}

// ---- fallback (no workspace): direct strided gather -----------------------
__global__ void zero_out_k(float* out) { if (threadIdx.x == 0) out[0] = 0.0f; }

__global__ __launch_bounds__(256) void kvl_fallback_k(
        const float* __restrict__ c, const float* __restrict__ s,
        const float* __restrict__ signs, const int* __restrict__ inds,
        const int* __restrict__ rows, int E, float* __restrict__ out) {
    const int r = blockIdx.x;
    int lo = 0, hi = E;
    while (lo < hi) { const int m = (lo + hi) >> 1; if (rows[m] < r) lo = m + 1; else hi = m; }
    const int start = lo;
    hi = E;
    while (lo < hi) { const int m = (lo + hi) >> 1; if (rows[m] <= r) lo = m + 1; else hi = m; }
    const int end = lo;
    const int tid = threadIdx.x;
    float acc = 0.f;
    for (int e = start; e < end; ++e) {
        const int idx = inds[e];
        const float sg = signs[e];
        acc += atan2f(sg * s[(size_t)tid * NB + idx], c[(size_t)tid * NB + idx]);
    }
    float v = fabsf(acc);
    #pragma unroll
    for (int off = 32; off > 0; off >>= 1)
        v += __shfl_down(v, off, 64);
    __shared__ float wsum[4];
    if ((tid & 63) == 0) wsum[tid >> 6] = v;
    __syncthreads();
    if (tid == 0)
        atomicAdd(out, (wsum[0] + wsum[1] + wsum[2] + wsum[3]) *
                       (1.0f / ((float)NCYC * (float)BATCH)));
}

extern "C" void kernel_launch(void* const* d_in, const int* in_sizes, int n_in,
                              void* d_out, int out_size, void* d_ws, size_t ws_size,
                              hipStream_t stream) {
    const float* c       = (const float*)d_in[0];
    const float* s       = (const float*)d_in[1];
    const float* cysigns = (const float*)d_in[2];
    const int*   cyinds  = (const int*)d_in[3];
    const int*   cyrows  = (const int*)d_in[4];
    const int    E       = in_sizes[2];   // 160000
    float* out = (float*)d_out;

    const size_t th_bytes = (size_t)NB * BATCH;           // 12.8 MB int8
    const size_t need = th_bytes
                      + (size_t)NCYC * sizeof(float)      // partials
                      + sizeof(int);                       // counter
    if (ws_size >= need) {
        signed char* th     = (signed char*)d_ws;
        float* partials     = (float*)(th + th_bytes);
        int*   counter      = (int*)(partials + NCYC);

        dim3 tg((NB4 + 15) / 16, BATCH / 64);             // (782, 4)
        theta_k<<<tg, 256, 0, stream>>>((const float4*)c, (const float4*)s, th, counter);
        kvl_main_k<<<NCYC / 4, 256, 0, stream>>>(th, cysigns, cyinds, cyrows, E,
                                                 partials, counter, out);
    } else {
        zero_out_k<<<1, 64, 0, stream>>>(out);
        kvl_fallback_k<<<NCYC, 256, 0, stream>>>(c, s, cysigns, cyinds, cyrows, E, out);
    }
}

// Round 5
// 162.725 us; speedup vs baseline: 3.2545x; 3.2545x over previous
//
#include <hip/hip_runtime.h>

#define NB     50000
#define NB4    12500
#define BATCH  256
#define NCYC   20000
#define QSCALE  (127.0f / 3.14159265358979f)
#define DQSCALE (3.14159265358979f / 127.0f)

// ---- fused: transpose + atan2 + int8 quantize -> th[NB][BATCH] ------------
// atan2(g*s, c) = g * atan2(s, c) for g=+-1, so one atan2 per (b, branch).
// Tile: 64 b x 64 nb. Block 256.
__global__ __launch_bounds__(256) void theta_k(
        const float4* __restrict__ c4, const float4* __restrict__ s4,
        signed char* __restrict__ th) {
    __shared__ signed char t[64][68];       // [b_local][nb_local], 68 = 4*17
    const int u    = threadIdx.x;
    const int col4 = u & 15;                // nb4 within tile
    const int brow = u >> 4;                // 0..15
    const int x4   = blockIdx.x * 16 + col4;
    const int bb   = blockIdx.y * 64;

    if (x4 < NB4) {
        #pragma unroll
        for (int j = 0; j < 4; ++j) {
            const int bl = brow + 16 * j;   // b_local 0..63
            const float4 vc = c4[(size_t)(bb + bl) * NB4 + x4];
            const float4 vs = s4[(size_t)(bb + bl) * NB4 + x4];
            char4 q;
            q.x = (signed char)__float2int_rn(atan2f(vs.x, vc.x) * QSCALE);
            q.y = (signed char)__float2int_rn(atan2f(vs.y, vc.y) * QSCALE);
            q.z = (signed char)__float2int_rn(atan2f(vs.z, vc.z) * QSCALE);
            q.w = (signed char)__float2int_rn(atan2f(vs.w, vc.w) * QSCALE);
            *reinterpret_cast<char4*>(&t[bl][4 * col4]) = q;
        }
    }
    __syncthreads();
    // store phase: 16 lanes cover 64 consecutive b (64B) per nb
    const int g   = u & 15;                 // char4 group along b
    const int nb0 = u >> 4;                 // 0..15
    #pragma unroll
    for (int j = 0; j < 4; ++j) {
        const int nbl = nb0 + 16 * j;       // 0..63
        const int nb  = blockIdx.x * 64 + nbl;
        if (nb < NB) {
            char4 v;
            v.x = t[4 * g + 0][nbl];
            v.y = t[4 * g + 1][nbl];
            v.z = t[4 * g + 2][nbl];
            v.w = t[4 * g + 3][nbl];
            *reinterpret_cast<char4*>(&th[(size_t)nb * BATCH + bb + 4 * g]) = v;
        }
    }
}

// ---- main: wave per row (4/block), self-computed bounds, NO fences --------
__global__ __launch_bounds__(256) void kvl_main_k(
        const signed char* __restrict__ th,
        const float* __restrict__ signs, const int* __restrict__ inds,
        const int* __restrict__ rows, int E,
        float* __restrict__ partials) {
    __shared__ int bnd[5];
    const int tid = threadIdx.x;
    const int r0  = blockIdx.x * 4;
    if (tid < 5) {
        const int target = r0 + tid;
        int lo = 0, hi = E;
        while (lo < hi) { const int m = (lo + hi) >> 1; if (rows[m] < target) lo = m + 1; else hi = m; }
        bnd[tid] = lo;
    }
    __syncthreads();
    const int wave  = tid >> 6;
    const int lane  = tid & 63;
    const int start = bnd[wave];
    const int end   = bnd[wave + 1];

    float a0 = 0.f, a1 = 0.f, a2 = 0.f, a3 = 0.f;
    int e = start;
    for (; e + 2 <= end; e += 2) {
        const int   i0 = inds[e],  i1 = inds[e + 1];
        const float g0 = signs[e] * DQSCALE, g1 = signs[e + 1] * DQSCALE;
        const unsigned int u0 = *reinterpret_cast<const unsigned int*>(&th[(size_t)i0 * BATCH + lane * 4]);
        const unsigned int u1 = *reinterpret_cast<const unsigned int*>(&th[(size_t)i1 * BATCH + lane * 4]);
        a0 += g0 * (float)(signed char)(u0      ) + g1 * (float)(signed char)(u1      );
        a1 += g0 * (float)(signed char)(u0 >>  8) + g1 * (float)(signed char)(u1 >>  8);
        a2 += g0 * (float)(signed char)(u0 >> 16) + g1 * (float)(signed char)(u1 >> 16);
        a3 += g0 * (float)(signed char)(u0 >> 24) + g1 * (float)(signed char)(u1 >> 24);
    }
    if (e < end) {
        const float g0 = signs[e] * DQSCALE;
        const unsigned int u0 = *reinterpret_cast<const unsigned int*>(&th[(size_t)inds[e] * BATCH + lane * 4]);
        a0 += g0 * (float)(signed char)(u0      );
        a1 += g0 * (float)(signed char)(u0 >>  8);
        a2 += g0 * (float)(signed char)(u0 >> 16);
        a3 += g0 * (float)(signed char)(u0 >> 24);
    }
    float v = fabsf(a0) + fabsf(a1) + fabsf(a2) + fabsf(a3);
    #pragma unroll
    for (int off = 32; off > 0; off >>= 1)
        v += __shfl_down(v, off, 64);
    if (lane == 0) partials[r0 + wave] = v;
}

// ---- final: single block reduces partials -> out[0] -----------------------
__global__ __launch_bounds__(1024) void reduce_k(
        const float* __restrict__ partials, float* __restrict__ out) {
    const int tid = threadIdx.x;
    float v = 0.f;
    for (int i = tid; i < NCYC; i += 1024) v += partials[i];
    #pragma unroll
    for (int off = 32; off > 0; off >>= 1)
        v += __shfl_down(v, off, 64);
    __shared__ float wsum[16];
    if ((tid & 63) == 0) wsum[tid >> 6] = v;
    __syncthreads();
    if (tid == 0) {
        float t = 0.f;
        #pragma unroll
        for (int w = 0; w < 16; ++w) t += wsum[w];
        out[0] = t * (1.0f / ((float)NCYC * (float)BATCH));
    }
}

// ---- fallback (no workspace): direct strided gather -----------------------
__global__ void zero_out_k(float* out) { if (threadIdx.x == 0) out[0] = 0.0f; }

__global__ __launch_bounds__(256) void kvl_fallback_k(
        const float* __restrict__ c, const float* __restrict__ s,
        const float* __restrict__ signs, const int* __restrict__ inds,
        const int* __restrict__ rows, int E, float* __restrict__ out) {
    const int r = blockIdx.x;
    int lo = 0, hi = E;
    while (lo < hi) { const int m = (lo + hi) >> 1; if (rows[m] < r) lo = m + 1; else hi = m; }
    const int start = lo;
    hi = E;
    while (lo < hi) { const int m = (lo + hi) >> 1; if (rows[m] <= r) lo = m + 1; else hi = m; }
    const int end = lo;
    const int tid = threadIdx.x;
    float acc = 0.f;
    for (int e = start; e < end; ++e) {
        const int idx = inds[e];
        const float sg = signs[e];
        acc += atan2f(sg * s[(size_t)tid * NB + idx], c[(size_t)tid * NB + idx]);
    }
    float v = fabsf(acc);
    #pragma unroll
    for (int off = 32; off > 0; off >>= 1)
        v += __shfl_down(v, off, 64);
    __shared__ float wsum[4];
    if ((tid & 63) == 0) wsum[tid >> 6] = v;
    __syncthreads();
    if (tid == 0)
        atomicAdd(out, (wsum[0] + wsum[1] + wsum[2] + wsum[3]) *
                       (1.0f / ((float)NCYC * (float)BATCH)));
}

extern "C" void kernel_launch(void* const* d_in, const int* in_sizes, int n_in,
                              void* d_out, int out_size, void* d_ws, size_t ws_size,
                              hipStream_t stream) {
    const float* c       = (const float*)d_in[0];
    const float* s       = (const float*)d_in[1];
    const float* cysigns = (const float*)d_in[2];
    const int*   cyinds  = (const int*)d_in[3];
    const int*   cyrows  = (const int*)d_in[4];
    const int    E       = in_sizes[2];   // 160000
    float* out = (float*)d_out;

    const size_t th_bytes = (size_t)NB * BATCH;           // 12.8 MB int8
    const size_t need = th_bytes + (size_t)NCYC * sizeof(float);
    if (ws_size >= need) {
        signed char* th = (signed char*)d_ws;
        float* partials = (float*)(th + th_bytes);

        dim3 tg((NB4 + 15) / 16, BATCH / 64);             // (782, 4)
        theta_k<<<tg, 256, 0, stream>>>((const float4*)c, (const float4*)s, th);
        kvl_main_k<<<NCYC / 4, 256, 0, stream>>>(th, cysigns, cyinds, cyrows, E, partials);
        reduce_k<<<1, 1024, 0, stream>>>(partials, out);
    } else {
        zero_out_k<<<1, 64, 0, stream>>>(out);
        kvl_fallback_k<<<NCYC, 256, 0, stream>>>(c, s, cysigns, cyinds, cyrows, E, out);
    }
}